// Round 10
// baseline (6392.054 us; speedup 1.0000x reference)
//
#include <hip/hip_runtime.h>

#define Bdim 640
#define Hdim 768
#define PJdim 256
#define Tdim 160
#define NSTEP (Tdim + 2)
#define ZS 258   // zst row stride (floats)

typedef _Float16 half8 __attribute__((ext_vector_type(8)));
typedef float floatx4 __attribute__((ext_vector_type(4)));

// ---------------- workspace layout (halfs/bytes) ----------------
constexpr size_t HB_HALFS = 3ull * Bdim * PJdim;            // 491,520
constexpr size_t ZP_OFF   = HB_HALFS * 2;                   // byte offset
constexpr size_t MB_OFF   = ZP_OFF + 256;
constexpr size_t MB_HALFS = 3ull * Bdim * Hdim;             // 1,474,560
constexpr size_t X_OFF    = MB_OFF + MB_HALFS * 2;
constexpr size_t X_HALFS  = (size_t)Tdim * Bdim * 40;       // 4,096,000
constexpr size_t W_OFF    = X_OFF + X_HALFS * 2;
constexpr size_t W_HALFS  = 36ull * 131072;                 // 4,718,592
constexpr size_t P_OFF    = W_OFF + W_HALFS * 2;
constexpr size_t P_HALFS  = 3ull * 196608;                  // 589,824
constexpr size_t C_OFF    = P_OFF + P_HALFS * 2;
constexpr size_t C_BYTES  = 3ull * Bdim * Hdim * 4;

__device__ __forceinline__ float sigm(float v) { return 1.0f / (1.0f + __expf(-v)); }
__device__ __forceinline__ float tanh_fast(float v) { return 2.0f / (1.0f + __expf(-2.0f * v)) - 1.0f; }

// Device-coherent 16B load (bypass L1/L2, served from LLC).
// ONLY for cross-XCD h16 consumer edges (even gid, l>0 reading h(l-1)).
__device__ __forceinline__ uint4 ld_coh16(const void* p) {
    const unsigned long long* q = (const unsigned long long*)p;
    unsigned long long a = __hip_atomic_load(q,     __ATOMIC_RELAXED, __HIP_MEMORY_SCOPE_AGENT);
    unsigned long long b = __hip_atomic_load(q + 1, __ATOMIC_RELAXED, __HIP_MEMORY_SCOPE_AGENT);
    uint4 r; r.x = (unsigned)a; r.y = (unsigned)(a >> 32);
    r.z = (unsigned)b; r.w = (unsigned)(b >> 32);
    return r;
}
// Device-coherent 2B store (to LLC). ONLY for cross-XCD h16 producer edges.
__device__ __forceinline__ void st_coh16b(void* p, _Float16 h) {
    union { _Float16 h; unsigned short u; } cv; cv.h = h;
    __hip_atomic_store((unsigned short*)p, cv.u, __ATOMIC_RELAXED, __HIP_MEMORY_SCOPE_AGENT);
}

// ---------------- fine-grained pipeline sync (R7 semantics: sc0-only acquire) ----
// Flag layout per gid (256-word region): gd=+0, pd=+8, gdh[ht]=+16+16*ht.
__device__ __forceinline__ void wait1(unsigned* c, unsigned tgt)
{
    if (threadIdx.x == 0) {
        while (__hip_atomic_load(c, __ATOMIC_RELAXED, __HIP_MEMORY_SCOPE_AGENT) < tgt)
            __builtin_amdgcn_s_sleep(1);
    }
    asm volatile("buffer_inv sc0" ::: "memory");   // L1-only invalidate (R7-proven)
    __syncthreads();
}

__device__ __forceinline__ void wait2(unsigned* a, unsigned* b, unsigned tgt)
{
    if (threadIdx.x == 0) {
        while (__hip_atomic_load(a, __ATOMIC_RELAXED, __HIP_MEMORY_SCOPE_AGENT) < tgt)
            __builtin_amdgcn_s_sleep(1);
        while (__hip_atomic_load(b, __ATOMIC_RELAXED, __HIP_MEMORY_SCOPE_AGENT) < tgt)
            __builtin_amdgcn_s_sleep(1);
    }
    asm volatile("buffer_inv sc0" ::: "memory");
    __syncthreads();
}

__device__ __forceinline__ void pipe_sig(unsigned* c)
{
    __syncthreads();                // drains vmcnt: write-through stores in L2/LLC
    if (threadIdx.x == 0)
        __hip_atomic_fetch_add(c, 1u, __ATOMIC_RELAXED, __HIP_MEMORY_SCOPE_AGENT);
}

__device__ __forceinline__ void pipe_sig2(unsigned* a, unsigned* b)
{
    __syncthreads();
    if (threadIdx.x == 0) {
        __hip_atomic_fetch_add(a, 1u, __ATOMIC_RELAXED, __HIP_MEMORY_SCOPE_AGENT);
        __hip_atomic_fetch_add(b, 1u, __ATOMIC_RELAXED, __HIP_MEMORY_SCOPE_AGENT);
    }
}

// ---------------- one-time repack: fragment-ordered fp16 images (unchanged) ----------------
__global__ void repack_kernel(const float* __restrict__ x,
                              const float* __restrict__ W0, const float* __restrict__ W1,
                              const float* __restrict__ W2, const float* __restrict__ P0,
                              const float* __restrict__ P1, const float* __restrict__ P2,
                              _Float16* __restrict__ Wfrag, _Float16* __restrict__ Pfrag,
                              _Float16* __restrict__ x16)
{
    size_t idx = (size_t)blockIdx.x * 256 + threadIdx.x;
    if (idx < W_HALFS) {
        int slab = (int)(idx >> 17);          // /131072
        int l = slab / 12, ht = slab % 12;
        int r  = (int)(idx & 131071);
        int kc = r >> 13;                      // /8192
        int r2 = r & 8191;
        int g  = r2 >> 11;
        int cf = (r2 >> 9) & 3;
        int u  = r2 & 511;
        int lane = u >> 3, e = u & 7;
        int qd = lane >> 4, ln = lane & 15;
        int k   = kc * 32 + qd * 8 + e;
        int col = g * Hdim + ht * 64 + cf * 16 + ln;
        float v;
        if (l == 0)      v = (k < 296) ? W0[(size_t)k * 3072 + col] : 0.0f;
        else if (l == 1) v = W1[(size_t)k * 3072 + col];
        else             v = W2[(size_t)k * 3072 + col];
        Wfrag[idx] = (_Float16)v;
    } else if (idx < W_HALFS + P_HALFS) {
        size_t i = idx - W_HALFS;
        int l = (int)(i / 196608);
        int r = (int)(i % 196608);
        int cq = r / 49152;
        int r2 = r % 49152;
        int kc = r2 / 2048;
        int r3 = r2 & 2047;
        int cgr = r3 >> 9;
        int u  = r3 & 511;
        int lane = u >> 3, e = u & 7;
        int qd = lane >> 4, ln = lane & 15;
        int k  = kc * 32 + qd * 8 + e;
        int pj = cq * 64 + cgr * 16 + ln;
        const float* P = (l == 0) ? P0 : (l == 1) ? P1 : P2;
        Pfrag[i] = (_Float16)P[(size_t)k * PJdim + pj];
    } else if (idx < W_HALFS + P_HALFS + X_HALFS) {
        size_t i = idx - W_HALFS - P_HALFS;
        x16[i] = (_Float16)x[i];
    }
}

// ---------------- gate step: DEPTH-2 staged ring (R10 change) ----------------
// Ring: 6 slots x 8KB (3 x 2-kc chunks). Loads for chunk cp+2 issued during
// chunk cp -> ~1024cy (2 chunk-bodies) of latency cover vs ~512cy at depth-1.
// Slot WAR: slot set (cp%3) rewritten at cp+3, >= 2 barriers after readers.
__device__ __forceinline__ void gate_step(
    int l, int b0r, int h0, int t, bool xl,
    const half8 (&Breg)[16][2], float (&c)[16],
    const _Float16* __restrict__ x16, const _Float16* __restrict__ h16,
    const _Float16* __restrict__ zerop, _Float16* __restrict__ mbuf,
    _Float16* __restrict__ Ast, float* __restrict__ zst, const float* __restrict__ bst,
    unsigned* pd, unsigned pdt, unsigned* pdlo, unsigned pdlot, int tid)
{
    const int wv = tid >> 6, lane = tid & 63, qd = lane >> 4, ln = lane & 15;
    const int g = wv >> 1, hh = wv & 1;
    const int qd8 = qd * 8;
    const int rowg = b0r + wv * 16 + ln;                    // staging row for this lane

    const _Float16* xt  = x16 + ((size_t)t * Bdim + rowg) * 40;
    const _Float16* h0b = h16 + (size_t)rowg * PJdim - 40;                       // l==0, k in [40,296)
    const _Float16* lob = (l > 0) ? h16 + ((size_t)(l - 1) * Bdim + rowg) * PJdim : nullptr;
    const _Float16* hib = h16 + ((size_t)l * Bdim + rowg) * PJdim - 256;         // l>0, k>=256

    auto srcp = [&](int kc) -> const _Float16* {
        int k = kc * 32 + qd8;
        if (l == 0) return (k < 40) ? xt + k : (k < 296) ? h0b + k : zerop;
        return (k < 256) ? lob + k : hib + k;
    };

    floatx4 acc[8][2];
    const floatx4 fz = {0.f, 0.f, 0.f, 0.f};
#pragma unroll
    for (int i = 0; i < 8; ++i) { acc[i][0] = fz; acc[i][1] = fz; }

    _Float16* Aw = Ast + wv * 512 + lane * 8;

    auto stage_gemm = [&](int kc0, int nkc, bool coh) {
        const int ncp = nkc >> 1;                      // 4 or 5 chunks of 2 kc
        uint4 pa0, pa1, pb0, pb1;                      // 2 chunks in flight
        pa0 = coh ? ld_coh16(srcp(kc0))     : *(const uint4*)srcp(kc0);
        pa1 = coh ? ld_coh16(srcp(kc0 + 1)) : *(const uint4*)srcp(kc0 + 1);
        pb0 = coh ? ld_coh16(srcp(kc0 + 2)) : *(const uint4*)srcp(kc0 + 2);
        pb1 = coh ? ld_coh16(srcp(kc0 + 3)) : *(const uint4*)srcp(kc0 + 3);
#pragma unroll
        for (int cp = 0; cp < 5; ++cp) {
            if (cp < ncp) {
                const int s0 = (cp % 3) * 2;           // 6-slot ring
                _Float16* W0 = Aw + (size_t)s0 * 4096;
                if ((cp & 1) == 0) {
                    *(uint4*)W0          = pa0;
                    *(uint4*)(W0 + 4096) = pa1;
                    if (cp + 2 < ncp) {
                        pa0 = coh ? ld_coh16(srcp(kc0 + 2 * cp + 4)) : *(const uint4*)srcp(kc0 + 2 * cp + 4);
                        pa1 = coh ? ld_coh16(srcp(kc0 + 2 * cp + 5)) : *(const uint4*)srcp(kc0 + 2 * cp + 5);
                    }
                } else {
                    *(uint4*)W0          = pb0;
                    *(uint4*)(W0 + 4096) = pb1;
                    if (cp + 2 < ncp) {
                        pb0 = coh ? ld_coh16(srcp(kc0 + 2 * cp + 4)) : *(const uint4*)srcp(kc0 + 2 * cp + 4);
                        pb1 = coh ? ld_coh16(srcp(kc0 + 2 * cp + 5)) : *(const uint4*)srcp(kc0 + 2 * cp + 5);
                    }
                }
                __syncthreads();                       // chunk staged; ring WAR covered
#pragma unroll
                for (int j = 0; j < 2; ++j) {
                    const _Float16* Ab = Ast + (size_t)(s0 + j) * 4096;
                    const int kc = kc0 + 2 * cp + j;
#pragma unroll
                    for (int rf = 0; rf < 8; ++rf) {
                        half8 af = *(const half8*)(Ab + rf * 512 + lane * 8);
                        acc[rf][0] = __builtin_amdgcn_mfma_f32_16x16x32_f16(af, Breg[kc][0], acc[rf][0], 0, 0, 0);
                        acc[rf][1] = __builtin_amdgcn_mfma_f32_16x16x32_f16(af, Breg[kc][1], acc[rf][1], 0, 0, 0);
                    }
                }
            }
        }
    };

    if (pd) wait1(pd, pdt);                            // own h(l,t-1) + mbuf WAR
    if (l == 0) {
        stage_gemm(0, 10, false);
    } else {
        stage_gemm(8, 8, false);                       // own-recurrence half first
        if (pdlo) wait1(pdlo, pdlot);                  // lower layer h(l-1,t) [barrier separates ring reuse]
        stage_gemm(0, 8, xl);                          // lob half (coherent if cross-XCD)
    }
    __syncthreads();                                   // last MFMA reads done; zst aliases ring

    // ---- z write-all (one pass)
#pragma unroll
    for (int rf = 0; rf < 8; ++rf)
#pragma unroll
        for (int cf = 0; cf < 2; ++cf)
#pragma unroll
            for (int r = 0; r < 4; ++r)
                zst[(size_t)(rf * 16 + qd * 4 + r) * ZS + g * 64 + hh * 32 + cf * 16 + ln]
                    = acc[rf][cf][r];
    __syncthreads();

    // ---- elementwise: thread owns (row, 16 cols)
    const int row = tid >> 2, c0 = (tid & 3) * 16;
    const float* zrow = zst + (size_t)row * ZS;
    union { _Float16 h[16]; uint4 v[2]; } pk;
#pragma unroll
    for (int q = 0; q < 4; ++q) {
        const int o = q * 4;
        float4 zi = *(const float4*)(zrow + c0 + o);
        float4 zj = *(const float4*)(zrow + 64 + c0 + o);
        float4 zf = *(const float4*)(zrow + 128 + c0 + o);
        float4 zo = *(const float4*)(zrow + 192 + c0 + o);
        float4 bi = *(const float4*)(bst + c0 + o);
        float4 bj = *(const float4*)(bst + 64 + c0 + o);
        float4 bf = *(const float4*)(bst + 128 + c0 + o);
        float4 bo = *(const float4*)(bst + 192 + c0 + o);
        float cn0 = sigm(zf.x + bf.x) * c[o + 0] + sigm(zi.x + bi.x) * tanh_fast(zj.x + bj.x);
        float cn1 = sigm(zf.y + bf.y) * c[o + 1] + sigm(zi.y + bi.y) * tanh_fast(zj.y + bj.y);
        float cn2 = sigm(zf.z + bf.z) * c[o + 2] + sigm(zi.z + bi.z) * tanh_fast(zj.z + bj.z);
        float cn3 = sigm(zf.w + bf.w) * c[o + 3] + sigm(zi.w + bi.w) * tanh_fast(zj.w + bj.w);
        c[o + 0] = cn0; c[o + 1] = cn1; c[o + 2] = cn2; c[o + 3] = cn3;
        pk.h[o + 0] = (_Float16)(sigm(zo.x + bo.x) * tanh_fast(cn0));
        pk.h[o + 1] = (_Float16)(sigm(zo.y + bo.y) * tanh_fast(cn1));
        pk.h[o + 2] = (_Float16)(sigm(zo.z + bo.z) * tanh_fast(cn2));
        pk.h[o + 3] = (_Float16)(sigm(zo.w + bo.w) * tanh_fast(cn3));
    }
    _Float16* mb = mbuf + ((size_t)l * Bdim + b0r + row) * Hdim + h0 + c0;
    *(uint4*)mb       = pk.v[0];
    *(uint4*)(mb + 8) = pk.v[1];
}

// ---------------- proj step: DEPTH-2 staged regions + per-ht pair waits ----------------
// 3 regions x 32KB (4-kc chunks). Chunk ch+2's loads issued during ch. One
// barrier per chunk (the wait2/syncthreads doubles as the staging barrier).
// Region WAR: region (ch%3) rewritten at ch+3, 2 barriers after readers.
__device__ __forceinline__ void proj_step(
    int l, int b0r, int cq, const half8 (&Preg)[24],
    const _Float16* __restrict__ mbuf, _Float16* __restrict__ h16,
    _Float16* __restrict__ AstBase, int tid, bool xstore,
    unsigned* gdhb, unsigned tgt)
{
    const int wv = tid >> 6, lane = tid & 63, qd = lane >> 4, ln = lane & 15;
    const int rh = wv >> 2, cgi = wv & 3;
    const int rowg = b0r + wv * 16 + ln;
    const _Float16* mrow = mbuf + ((size_t)l * Bdim + rowg) * Hdim + qd * 8;

    floatx4 pacc[4];
    const floatx4 fz = {0.f, 0.f, 0.f, 0.f};
#pragma unroll
    for (int i = 0; i < 4; ++i) pacc[i] = fz;

    uint4 pa[4], pb[4];
    if (gdhb) wait2(gdhb + 0, gdhb + 16, tgt);          // slabs 0,1 ready
#pragma unroll
    for (int k = 0; k < 4; ++k) pa[k] = *(const uint4*)(mrow + k * 32);
    if (gdhb) wait2(gdhb + 32, gdhb + 48, tgt);         // slabs 2,3 ready
#pragma unroll
    for (int k = 0; k < 4; ++k) pb[k] = *(const uint4*)(mrow + (4 + k) * 32);

#pragma unroll
    for (int ch = 0; ch < 6; ++ch) {
        _Float16* W = AstBase + (size_t)(ch % 3) * 16384 + wv * 512 + lane * 8;
        const _Float16* R = AstBase + (size_t)(ch % 3) * 16384;
        if ((ch & 1) == 0) {
#pragma unroll
            for (int k = 0; k < 4; ++k) *(uint4*)(W + (size_t)k * 4096) = pa[k];
        } else {
#pragma unroll
            for (int k = 0; k < 4; ++k) *(uint4*)(W + (size_t)k * 4096) = pb[k];
        }
        if (ch + 2 < 6) {
            // barrier (inside wait2 / explicit): makes chunk ch visible AND
            // orders the next pair's flags before its loads.
            if (gdhb) wait2(gdhb + (size_t)(2 * (ch + 2)) * 16,
                            gdhb + (size_t)(2 * (ch + 2) + 1) * 16, tgt);
            else __syncthreads();
            if ((ch & 1) == 0) {
#pragma unroll
                for (int k = 0; k < 4; ++k) pa[k] = *(const uint4*)(mrow + ((ch + 2) * 4 + k) * 32);
            } else {
#pragma unroll
                for (int k = 0; k < 4; ++k) pb[k] = *(const uint4*)(mrow + ((ch + 2) * 4 + k) * 32);
            }
        } else {
            __syncthreads();
        }
#pragma unroll
        for (int kk = 0; kk < 4; ++kk) {
            const _Float16* Ab = R + (size_t)kk * 4096;
#pragma unroll
            for (int rfl = 0; rfl < 4; ++rfl) {
                half8 af = *(const half8*)(Ab + (rh * 4 + rfl) * 512 + lane * 8);
                pacc[rfl] = __builtin_amdgcn_mfma_f32_16x16x32_f16(af, Preg[ch * 4 + kk], pacc[rfl], 0, 0, 0);
            }
        }
    }

    if (xstore) {
#pragma unroll
        for (int rfl = 0; rfl < 4; ++rfl)
#pragma unroll
            for (int r = 0; r < 4; ++r) {
                int row = b0r + (rh * 4 + rfl) * 16 + qd * 4 + r;
                st_coh16b(h16 + ((size_t)l * Bdim + row) * PJdim + cq * 64 + cgi * 16 + ln,
                          (_Float16)pacc[rfl][r]);
            }
    } else {
#pragma unroll
        for (int rfl = 0; rfl < 4; ++rfl)
#pragma unroll
            for (int r = 0; r < 4; ++r) {
                int row = b0r + (rh * 4 + rfl) * 16 + qd * 4 + r;
                h16[((size_t)l * Bdim + row) * PJdim + cq * 64 + cgi * 16 + ln] = (_Float16)pacc[rfl][r];
            }
    }
}

__device__ __forceinline__ void load_Breg(const _Float16* __restrict__ Wfrag, int l, int ht,
                                          int wv, int lane, half8 (&Breg)[16][2])
{
    const int g = wv >> 1, hh = wv & 1;
    const _Float16* wslab = Wfrag + ((size_t)(l * 12 + ht)) * 131072;
#pragma unroll
    for (int kc = 0; kc < 16; ++kc)
#pragma unroll
        for (int cf = 0; cf < 2; ++cf)
            Breg[kc][cf] = *(const half8*)(wslab + kc * 8192 + g * 2048 + (hh * 2 + cf) * 512 + lane * 8);
}

__device__ __forceinline__ void load_Preg(const _Float16* __restrict__ Pfrag, int l, int cq,
                                          int wv, int lane, half8 (&Preg)[24])
{
    const int cgi = wv & 3;
    const _Float16* pslab = Pfrag + (size_t)l * 196608 + (size_t)cq * 49152;
#pragma unroll
    for (int kc = 0; kc < 24; ++kc)
        Preg[kc] = *(const half8*)(pslab + kc * 2048 + cgi * 512 + lane * 8);
}

__device__ __forceinline__ void load_bst(const float* __restrict__ bias, int h0, int tid,
                                         float* __restrict__ bst)
{
    if (tid < 256) {
        int gg = tid >> 6, u = tid & 63;
        bst[tid] = bias[gg * Hdim + h0 + u] + ((gg == 2) ? 1.0f : 0.0f);  // forget bias folded
    }
}

__device__ __forceinline__ void finalize_row(const _Float16* __restrict__ h16,
                                             float* __restrict__ out, int row, int lane)
{
    const _Float16* e = h16 + ((size_t)2 * Bdim + row) * PJdim + lane * 4;
    float v0 = (float)e[0], v1 = (float)e[1], v2 = (float)e[2], v3 = (float)e[3];
    float ss = v0 * v0 + v1 * v1 + v2 * v2 + v3 * v3;
#pragma unroll
    for (int o = 32; o > 0; o >>= 1) ss += __shfl_xor(ss, o, 64);
    float rs = rsqrtf(fmaxf(ss, 1e-12f));
    float4 o4; o4.x = v0 * rs; o4.y = v1 * rs; o4.z = v2 * rs; o4.w = v3 * rs;
    *(float4*)(out + (size_t)row * PJdim + lane * 4) = o4;
}

// ---------------- persistent kernel (R9 structure + depth-2 staging) ----------------
// Hazard/coherence audit identical to R9 (per-gid flags: gd=+0, pd=+8,
// gdh[ht]=+16+16*ht; sc0-only acquire; coherent cross-XCD h16 edges).
// LDS (133KB, 1 block/CU): gate ring 6x8KB at [0,48K) aliases zst[0,132096);
// bst at 132096. proj: 3 regions x 32KB at [0,96K).
__global__ __launch_bounds__(512)
void lstm_persist(const _Float16* __restrict__ x16, const _Float16* __restrict__ Wfrag,
                  const _Float16* __restrict__ Pfrag,
                  const float* __restrict__ bias0, const float* __restrict__ bias1,
                  const float* __restrict__ bias2,
                  _Float16* __restrict__ h16, _Float16* __restrict__ mbuf,
                  const _Float16* __restrict__ zerop, float* __restrict__ out,
                  unsigned* __restrict__ flags)
{
    __shared__ __align__(16) char LDSRAW[133120];
    _Float16* Ast  = (_Float16*)LDSRAW;
    float*    zst  = (float*)LDSRAW;
    float*    bst  = (float*)(LDSRAW + 132096);

    const int tid = threadIdx.x, bid = blockIdx.x;
    const int wv = tid >> 6, lane = tid & 63;

    // XCD-grouped role mapping: gid lives on XCD gid>>1 (assuming bid%8=XCD)
    const int xcd = bid & 7, slot = bid >> 3;
    const int gid = xcd * 2 + (slot >> 4);
    const int rr  = slot & 15;
    if (gid >= 15) return;                              // 16 idle blocks exit
    const int bt2 = gid / 3, l = gid % 3;
    const int b0r = bt2 * 128;

    unsigned* gbase = flags + (size_t)gid * 256;
    unsigned* gd = gbase;                               // aggregate gate counter
    unsigned* pd = gbase + 8;                           // aggregate proj counter

    if (rr < 12) {                                      // ---- gate block ----
        const int ht = rr, h0 = ht * 64;
        const bool xl = ((gid & 1) == 0) && (l > 0);    // lob producer on other XCD
        unsigned* gdh_self = gbase + 16 + (size_t)ht * 16;
        half8 Breg[16][2];
        load_Breg(Wfrag, l, ht, wv, lane, Breg);
        load_bst((l == 0) ? bias0 : (l == 1) ? bias1 : bias2, h0, tid, bst);
        float c[16];
#pragma unroll
        for (int u = 0; u < 16; ++u) c[u] = 0.f;
        unsigned* pd_lo = (l > 0) ? flags + (size_t)(gid - 1) * 256 + 8 : nullptr;
        for (int t = 0; t < Tdim; ++t) {
            gate_step(l, b0r, h0, t, xl, Breg, c, x16, h16, zerop, mbuf,
                      Ast, zst, bst,
                      pd, 4u * (unsigned)t,
                      pd_lo, (l > 0) ? 4u * (unsigned)(t + 1) : 0u, tid);
            pipe_sig2(gd, gdh_self);
        }
        if (l == 2 && rr < 8) {                         // finalize: 8 blocks x 16 rows per gid
            wait1(pd, 4u * (unsigned)Tdim);             // same-XCD producer; L1 inv suffices
            int row0 = b0r + rr * 16 + wv * 2;
            finalize_row(h16, out, row0, lane);
            finalize_row(h16, out, row0 + 1, lane);
        }
    } else {                                            // ---- proj block ----
        const int cq = rr - 12;
        const bool xstore = ((gid & 1) == 1) && (gid + 1 < 15) && ((gid + 1) % 3 != 0);
        unsigned* gdhb = gbase + 16;
        half8 Preg[24];
        load_Preg(Pfrag, l, cq, wv, lane, Preg);
        unsigned* gd_hi = (l < 2) ? flags + (size_t)(gid + 1) * 256 : nullptr;
        for (int t = 0; t < Tdim; ++t) {
            if (gd_hi && t > 0) wait1(gd_hi, 12u * (unsigned)t);   // h16 WAR vs gate(l+1,t-1)
            proj_step(l, b0r, cq, Preg, mbuf, h16,
                      Ast, tid, xstore, gdhb, (unsigned)(t + 1));
            pipe_sig(pd);
        }
    }
}

// ---------------- fallback: per-step kernels, c-state in global ----------------
__global__ __launch_bounds__(512)
void gate_fb(const _Float16* __restrict__ x16, const _Float16* __restrict__ Wfrag,
             const float* __restrict__ bias0, const float* __restrict__ bias1,
             const float* __restrict__ bias2,
             _Float16* __restrict__ h16, _Float16* __restrict__ mbuf,
             const _Float16* __restrict__ zerop, float* __restrict__ cfb, int s)
{
    __shared__ __align__(16) char LDSRAW[133120];
    _Float16* Ast  = (_Float16*)LDSRAW;
    float*    zst  = (float*)LDSRAW;
    float*    bst  = (float*)(LDSRAW + 132096);
    const int tid = threadIdx.x, bid = blockIdx.x;
    const int ht = bid % 12, z = bid / 12, l = z % 3, bt2 = z / 3;
    const int t = s - l;
    if (t < 0 || t >= Tdim) return;
    const int wv = tid >> 6, lane = tid & 63;
    const int b0r = bt2 * 128, h0 = ht * 64;
    half8 Breg[16][2];
    load_Breg(Wfrag, l, ht, wv, lane, Breg);
    load_bst((l == 0) ? bias0 : (l == 1) ? bias1 : bias2, h0, tid, bst);
    __syncthreads();
    const int row = tid >> 2, c0 = (tid & 3) * 16;
    float c[16];
#pragma unroll
    for (int u = 0; u < 16; ++u)
        c[u] = cfb[((size_t)l * Bdim + b0r + row) * Hdim + h0 + c0 + u];
    gate_step(l, b0r, h0, t, false, Breg, c, x16, h16, zerop, mbuf, Ast, zst, bst,
              nullptr, 0u, nullptr, 0u, tid);
#pragma unroll
    for (int u = 0; u < 16; ++u)
        cfb[((size_t)l * Bdim + b0r + row) * Hdim + h0 + c0 + u] = c[u];
}

__global__ __launch_bounds__(512)
void proj_fb(const _Float16* __restrict__ Pfrag, const _Float16* __restrict__ mbuf,
             _Float16* __restrict__ h16, int s)
{
    __shared__ __align__(16) char LDSRAW[98304];
    const int tid = threadIdx.x, bid = blockIdx.x;
    const int cq = bid & 3, z = bid >> 2, l = z % 3, bt2 = z / 3;
    const int tp = s - l;
    if (tp < 0 || tp >= Tdim) return;
    const int wv = tid >> 6, lane = tid & 63;
    half8 Preg[24];
    load_Preg(Pfrag, l, cq, wv, lane, Preg);
    proj_step(l, bt2 * 128, cq, Preg, mbuf, h16,
              (_Float16*)LDSRAW, tid, false, nullptr, 0u);
}

__global__ __launch_bounds__(512)
void fin_fb(const _Float16* __restrict__ h16, float* __restrict__ out)
{
    int row = blockIdx.x * 8 + (threadIdx.x >> 6);
    finalize_row(h16, out, row, threadIdx.x & 63);
}

extern "C" void kernel_launch(void* const* d_in, const int* in_sizes, int n_in,
                              void* d_out, int out_size, void* d_ws, size_t ws_size,
                              hipStream_t stream)
{
    (void)in_sizes; (void)n_in; (void)out_size; (void)ws_size;
    const float* x  = (const float*)d_in[0];
    const float* W0 = (const float*)d_in[1];
    const float* b0 = (const float*)d_in[2];
    const float* P0 = (const float*)d_in[3];
    const float* W1 = (const float*)d_in[4];
    const float* b1 = (const float*)d_in[5];
    const float* P1 = (const float*)d_in[6];
    const float* W2 = (const float*)d_in[7];
    const float* b2 = (const float*)d_in[8];
    const float* P2 = (const float*)d_in[9];

    char* ws = (char*)d_ws;
    _Float16* h16   = (_Float16*)(ws);
    _Float16* zerop = (_Float16*)(ws + ZP_OFF);
    _Float16* mbuf  = (_Float16*)(ws + MB_OFF);
    _Float16* x16   = (_Float16*)(ws + X_OFF);
    _Float16* Wfrag = (_Float16*)(ws + W_OFF);
    _Float16* Pfrag = (_Float16*)(ws + P_OFF);
    float*    cfb   = (float*)(ws + C_OFF);
    unsigned* flags = (unsigned*)(ws + C_OFF);   // coop path only; aliases cfb (fallback-only)
    float*    outp  = (float*)d_out;

    // zero h state + zero page (+ fallback c / pipe flags — same region)
    hipMemsetAsync(ws, 0, ZP_OFF + 256, stream);
    hipMemsetAsync(cfb, 0, C_BYTES, stream);

    {
        constexpr size_t total = W_HALFS + P_HALFS + X_HALFS;
        int grid = (int)((total + 255) / 256);
        repack_kernel<<<grid, 256, 0, stream>>>(x, W0, W1, W2, P0, P1, P2, Wfrag, Pfrag, x16);
    }

    int occ = 0;
    hipError_t oe = hipOccupancyMaxActiveBlocksPerMultiprocessor(&occ, lstm_persist, 512, 0);
    bool coop = (oe == hipSuccess && occ >= 1);
    if (coop) {
        void* args[] = { (void*)&x16, (void*)&Wfrag, (void*)&Pfrag,
                         (void*)&b0, (void*)&b1, (void*)&b2,
                         (void*)&h16, (void*)&mbuf, (void*)&zerop, (void*)&outp,
                         (void*)&flags };
        hipError_t le = hipLaunchCooperativeKernel((const void*)lstm_persist,
                                                   dim3(256), dim3(512), args, 0, stream);
        if (le != hipSuccess) { (void)hipGetLastError(); coop = false; }
    }
    if (!coop) {
        for (int s = 0; s < NSTEP; ++s) {
            gate_fb<<<180, 512, 0, stream>>>(x16, Wfrag, b0, b1, b2, h16, mbuf, zerop, cfb, s);
            proj_fb<<<60, 512, 0, stream>>>(Pfrag, mbuf, h16, s);
        }
        fin_fb<<<80, 512, 0, stream>>>(h16, outp);
    }
}

// Round 11
// 4756.123 us; speedup vs baseline: 1.3440x; 1.3440x over previous
//
#include <hip/hip_runtime.h>

#define Bdim 640
#define Hdim 768
#define PJdim 256
#define Tdim 160
#define NSTEP (Tdim + 2)

typedef _Float16 half8 __attribute__((ext_vector_type(8)));
typedef float floatx4 __attribute__((ext_vector_type(4)));

// ---------------- workspace layout (halfs/bytes) ----------------
constexpr size_t HB_HALFS = 3ull * Bdim * PJdim;            // 491,520
constexpr size_t ZP_OFF   = HB_HALFS * 2;                   // byte offset
constexpr size_t MB_OFF   = ZP_OFF + 256;
constexpr size_t MB_HALFS = 3ull * Bdim * Hdim;             // 1,474,560
constexpr size_t X_OFF    = MB_OFF + MB_HALFS * 2;
constexpr size_t X_HALFS  = (size_t)Tdim * Bdim * 40;       // 4,096,000
constexpr size_t W_OFF    = X_OFF + X_HALFS * 2;
constexpr size_t W_HALFS  = 36ull * 131072;                 // 4,718,592
constexpr size_t P_OFF    = W_OFF + W_HALFS * 2;
constexpr size_t P_HALFS  = 3ull * 196608;                  // 589,824
constexpr size_t C_OFF    = P_OFF + P_HALFS * 2;
constexpr size_t C_BYTES  = 3ull * Bdim * Hdim * 4;

__device__ __forceinline__ float sigm(float v) { return 1.0f / (1.0f + __expf(-v)); }
__device__ __forceinline__ float tanh_fast(float v) { return 2.0f / (1.0f + __expf(-2.0f * v)) - 1.0f; }

// Device-coherent 2B store (sc0 sc1: bypass L1/L2, lands at coherence point).
// Used ONLY by cross-XCD h16 producer edges (5 of 15 gids, 64KB/step each).
__device__ __forceinline__ void st_coh16b(void* p, _Float16 h) {
    union { _Float16 h; unsigned short u; } cv; cv.h = h;
    __hip_atomic_store((unsigned short*)p, cv.u, __ATOMIC_RELAXED, __HIP_MEMORY_SCOPE_AGENT);
}

// ---------------- fine-grained pipeline sync (session-best R3 semantics) ----------------
// Release: NO fence. __syncthreads drains vmcnt -> all normal stores are in the
// producer's XCD L2 (write-through L1), which same-XCD consumers share; cross-XCD
// data was stored coherently (st_coh16b) so it's at the LLC. Flag add is an
// agent-scope RMW at the coherence point.
// Acquire: buffer_inv only (acquire-agent fence): drops the consumer's STALE
// CLEAN lines; DIRTY lines -- the same-XCD producer's fresh data -- are
// preserved. No wbl2 sweep anywhere in the loop.
__device__ __forceinline__ void pipe_wait(unsigned* c0, unsigned t0, unsigned* c1, unsigned t1)
{
    if (threadIdx.x == 0) {
        if (t0)
            while (__hip_atomic_load(c0, __ATOMIC_RELAXED, __HIP_MEMORY_SCOPE_AGENT) < t0)
                __builtin_amdgcn_s_sleep(1);
        if (c1 && t1)
            while (__hip_atomic_load(c1, __ATOMIC_RELAXED, __HIP_MEMORY_SCOPE_AGENT) < t1)
                __builtin_amdgcn_s_sleep(1);
        __builtin_amdgcn_fence(__ATOMIC_ACQUIRE, "agent");   // buffer_inv, no wbl2
    }
    __syncthreads();
}

__device__ __forceinline__ void pipe_sig(unsigned* c)
{
    __syncthreads();                // drains vmcnt: stores visible at shared L2 / LLC
    if (threadIdx.x == 0)
        __hip_atomic_fetch_add(c, 1u, __ATOMIC_RELAXED, __HIP_MEMORY_SCOPE_AGENT);
}

// ---------------- one-time repack: fragment-ordered fp16 images ----------------
__global__ void repack_kernel(const float* __restrict__ x,
                              const float* __restrict__ W0, const float* __restrict__ W1,
                              const float* __restrict__ W2, const float* __restrict__ P0,
                              const float* __restrict__ P1, const float* __restrict__ P2,
                              _Float16* __restrict__ Wfrag, _Float16* __restrict__ Pfrag,
                              _Float16* __restrict__ x16)
{
    size_t idx = (size_t)blockIdx.x * 256 + threadIdx.x;
    if (idx < W_HALFS) {
        int slab = (int)(idx >> 17);          // /131072
        int l = slab / 12, ht = slab % 12;
        int r  = (int)(idx & 131071);
        int kc = r >> 13;                      // /8192
        int r2 = r & 8191;
        int g  = r2 >> 11;
        int cf = (r2 >> 9) & 3;
        int u  = r2 & 511;
        int lane = u >> 3, e = u & 7;
        int qd = lane >> 4, ln = lane & 15;
        int k   = kc * 32 + qd * 8 + e;
        int col = g * Hdim + ht * 64 + cf * 16 + ln;
        float v;
        if (l == 0)      v = (k < 296) ? W0[(size_t)k * 3072 + col] : 0.0f;
        else if (l == 1) v = W1[(size_t)k * 3072 + col];
        else             v = W2[(size_t)k * 3072 + col];
        Wfrag[idx] = (_Float16)v;
    } else if (idx < W_HALFS + P_HALFS) {
        size_t i = idx - W_HALFS;
        int l = (int)(i / 196608);
        int r = (int)(i % 196608);
        int cq = r / 49152;
        int r2 = r % 49152;
        int kc = r2 / 2048;
        int r3 = r2 & 2047;
        int cgr = r3 >> 9;
        int u  = r3 & 511;
        int lane = u >> 3, e = u & 7;
        int qd = lane >> 4, ln = lane & 15;
        int k  = kc * 32 + qd * 8 + e;
        int pj = cq * 64 + cgr * 16 + ln;
        const float* P = (l == 0) ? P0 : (l == 1) ? P1 : P2;
        Pfrag[i] = (_Float16)P[(size_t)k * PJdim + pj];
    } else if (idx < W_HALFS + P_HALFS + X_HALFS) {
        size_t i = idx - W_HALFS - P_HALFS;
        x16[i] = (_Float16)x[i];
    }
}

// ---------------- gate step body (one cell tile, one timestep) ----------------
// block: 128 rows x (4 gates x 64 hcols); 8 waves; wave (g=wv>>1, hh=wv&1) owns
// all 128 rows x 32 cols of gate g. Weights resident in Breg.
__device__ __forceinline__ void gate_step(
    int l, int b0r, int h0, int KC, int t,
    const half8 (&Breg)[16][2], float (&c)[8][2],
    const float (&bia)[2], const float (&bja)[2], const float (&bfa)[2], const float (&boa)[2],
    const _Float16* __restrict__ x16, const _Float16* __restrict__ h16,
    const _Float16* __restrict__ zerop, _Float16* __restrict__ mbuf,
    _Float16* __restrict__ Ast, float* __restrict__ zst, int tid)
{
    const int wv = tid >> 6, lane = tid & 63, qd = lane >> 4, ln = lane & 15;
    const int g = wv >> 1, hh = wv & 1;
    const int qd8 = qd * 8;
    const int rowg = b0r + wv * 16 + ln;                    // staging row for this lane

    const _Float16* xt  = x16 + ((size_t)t * Bdim + rowg) * 40;
    const _Float16* h0b = h16 + (size_t)rowg * PJdim - 40;                       // l==0, k in [40,296)
    const _Float16* lob = (l > 0) ? h16 + ((size_t)(l - 1) * Bdim + rowg) * PJdim : nullptr;
    const _Float16* hib = h16 + ((size_t)l * Bdim + rowg) * PJdim - 256;         // l>0, k>=256

    auto srcp = [&](int kc) -> const _Float16* {
        int k = kc * 32 + qd8;
        if (l == 0) return (k < 40) ? xt + k : (k < 296) ? h0b + k : zerop;
        return (k < 256) ? lob + k : hib + k;
    };

    floatx4 acc[8][2];
    const floatx4 fz = {0.f, 0.f, 0.f, 0.f};
#pragma unroll
    for (int i = 0; i < 8; ++i) { acc[i][0] = fz; acc[i][1] = fz; }

    const int CH = KC >> 1;                  // 5 (l==0) or 8 chunks of 64 k
    uint4 pre0 = *(const uint4*)srcp(0);
    uint4 pre1 = *(const uint4*)srcp(1);
#pragma unroll
    for (int ch = 0; ch < 8; ++ch) {
        if (ch < CH) {
            _Float16* Aw = Ast + (size_t)(ch & 1) * 8192 + wv * 512 + lane * 8;
            *(uint4*)Aw          = pre0;
            *(uint4*)(Aw + 4096) = pre1;
            if (ch + 1 < CH) {
                pre0 = *(const uint4*)srcp(2 * ch + 2);
                pre1 = *(const uint4*)srcp(2 * ch + 3);
            }
            __syncthreads();                 // chunk staged; double-buffer (ch&1) -> no WAR
            const _Float16* Ab = Ast + (size_t)(ch & 1) * 8192;
#pragma unroll
            for (int sub = 0; sub < 2; ++sub)
#pragma unroll
                for (int rf = 0; rf < 8; ++rf) {
                    half8 af = *(const half8*)(Ab + sub * 4096 + rf * 512 + lane * 8);
                    acc[rf][0] = __builtin_amdgcn_mfma_f32_16x16x32_f16(af, Breg[2 * ch + sub][0], acc[rf][0], 0, 0, 0);
                    acc[rf][1] = __builtin_amdgcn_mfma_f32_16x16x32_f16(af, Breg[2 * ch + sub][1], acc[rf][1], 0, 0, 0);
                }
        }
    }

    // elementwise: z through LDS in 8 row-passes of 16 rows
    const int trow = tid >> 5;            // 0..15
    const int hc0  = (tid * 2) & 63;      // even hcol
#pragma unroll
    for (int rf = 0; rf < 8; ++rf) {
        __syncthreads();                  // prev pass reads done (pass 0: gemm done per-wave; zst disjoint from Ast)
#pragma unroll
        for (int cf = 0; cf < 2; ++cf)
#pragma unroll
            for (int r = 0; r < 4; ++r)
                zst[(qd * 4 + r) * 256 + g * 64 + hh * 32 + cf * 16 + ln] = acc[rf][cf][r];
        __syncthreads();
        _Float16 mh[2];
#pragma unroll
        for (int j = 0; j < 2; ++j) {
            int hc = hc0 + j;
            float zi = zst[trow * 256 + hc]       + bia[j];
            float zj = zst[trow * 256 + 64 + hc]  + bja[j];
            float zf = zst[trow * 256 + 128 + hc] + bfa[j];
            float zo = zst[trow * 256 + 192 + hc] + boa[j];
            float cn = sigm(zf) * c[rf][j] + sigm(zi) * tanh_fast(zj);
            c[rf][j] = cn;
            mh[j] = (_Float16)(sigm(zo) * tanh_fast(cn));
        }
        union { _Float16 h2[2]; unsigned u; } pk;
        pk.h2[0] = mh[0]; pk.h2[1] = mh[1];
        int row_g = b0r + rf * 16 + trow;
        *(unsigned*)(mbuf + ((size_t)l * Bdim + row_g) * Hdim + h0 + hc0) = pk.u;   // normal: same-XCD consumer
    }
}

// ---------------- proj step body: 128 rows x 64 pjcols, K=768, P in regs ----------------
__device__ __forceinline__ void proj_step(
    int l, int b0r, int cq, const half8 (&Preg)[24],
    const _Float16* __restrict__ mbuf, _Float16* __restrict__ h16,
    _Float16* __restrict__ Ast, int tid, bool xstore)
{
    const int wv = tid >> 6, lane = tid & 63, qd = lane >> 4, ln = lane & 15;
    const int rh = wv >> 2, cgi = wv & 3;
    const int rowg = b0r + wv * 16 + ln;
    const _Float16* mrow = mbuf + ((size_t)l * Bdim + rowg) * Hdim + qd * 8;

    floatx4 pacc[4];
    const floatx4 fz = {0.f, 0.f, 0.f, 0.f};
#pragma unroll
    for (int i = 0; i < 4; ++i) pacc[i] = fz;

    uint4 pre0 = *(const uint4*)(mrow);
    uint4 pre1 = *(const uint4*)(mrow + 32);
#pragma unroll
    for (int ch = 0; ch < 12; ++ch) {
        _Float16* Aw = Ast + (size_t)(ch & 1) * 8192 + wv * 512 + lane * 8;
        *(uint4*)Aw          = pre0;
        *(uint4*)(Aw + 4096) = pre1;
        if (ch < 11) {
            pre0 = *(const uint4*)(mrow + (2 * ch + 2) * 32);
            pre1 = *(const uint4*)(mrow + (2 * ch + 3) * 32);
        }
        __syncthreads();
        const _Float16* Ab = Ast + (size_t)(ch & 1) * 8192;
#pragma unroll
        for (int sub = 0; sub < 2; ++sub)
#pragma unroll
            for (int rfl = 0; rfl < 4; ++rfl) {
                half8 af = *(const half8*)(Ab + sub * 4096 + (rh * 4 + rfl) * 512 + lane * 8);
                pacc[rfl] = __builtin_amdgcn_mfma_f32_16x16x32_f16(af, Preg[2 * ch + sub], pacc[rfl], 0, 0, 0);
            }
    }
    if (xstore) {
        // cross-XCD consumer exists (gate of gid+1 on the next XCD): store
        // device-coherent so the LLC holds fresh h; consumer's inv + cached
        // load refetches it. 64KB per gid-step, 5 of 15 gids.
#pragma unroll
        for (int rfl = 0; rfl < 4; ++rfl)
#pragma unroll
            for (int r = 0; r < 4; ++r) {
                int row = b0r + (rh * 4 + rfl) * 16 + qd * 4 + r;
                st_coh16b(h16 + ((size_t)l * Bdim + row) * PJdim + cq * 64 + cgi * 16 + ln,
                          (_Float16)pacc[rfl][r]);
            }
    } else {
#pragma unroll
        for (int rfl = 0; rfl < 4; ++rfl)
#pragma unroll
            for (int r = 0; r < 4; ++r) {
                int row = b0r + (rh * 4 + rfl) * 16 + qd * 4 + r;
                h16[((size_t)l * Bdim + row) * PJdim + cq * 64 + cgi * 16 + ln] = (_Float16)pacc[rfl][r];
            }
    }
}

__device__ __forceinline__ void load_Breg(const _Float16* __restrict__ Wfrag, int l, int ht,
                                          int wv, int lane, half8 (&Breg)[16][2])
{
    const int g = wv >> 1, hh = wv & 1;
    const _Float16* wslab = Wfrag + ((size_t)(l * 12 + ht)) * 131072;
#pragma unroll
    for (int kc = 0; kc < 16; ++kc)
#pragma unroll
        for (int cf = 0; cf < 2; ++cf)
            Breg[kc][cf] = *(const half8*)(wslab + kc * 8192 + g * 2048 + (hh * 2 + cf) * 512 + lane * 8);
}

__device__ __forceinline__ void load_Preg(const _Float16* __restrict__ Pfrag, int l, int cq,
                                          int wv, int lane, half8 (&Preg)[24])
{
    const int cgi = wv & 3;
    const _Float16* pslab = Pfrag + (size_t)l * 196608 + (size_t)cq * 49152;
#pragma unroll
    for (int kc = 0; kc < 24; ++kc)
        Preg[kc] = *(const half8*)(pslab + kc * 2048 + cgi * 512 + lane * 8);
}

__device__ __forceinline__ void load_bias(const float* __restrict__ bias, int h0, int tid,
                                          float (&bia)[2], float (&bja)[2], float (&bfa)[2], float (&boa)[2])
{
    int hcg = h0 + ((tid * 2) & 63);
#pragma unroll
    for (int j = 0; j < 2; ++j) {
        bia[j] = bias[hcg + j];
        bja[j] = bias[Hdim + hcg + j];
        bfa[j] = bias[2 * Hdim + hcg + j] + 1.0f;   // forget bias folded
        boa[j] = bias[3 * Hdim + hcg + j];
    }
}

__device__ __forceinline__ void finalize_row(const _Float16* __restrict__ h16,
                                             float* __restrict__ out, int row, int lane)
{
    const _Float16* e = h16 + ((size_t)2 * Bdim + row) * PJdim + lane * 4;
    float v0 = (float)e[0], v1 = (float)e[1], v2 = (float)e[2], v3 = (float)e[3];
    float ss = v0 * v0 + v1 * v1 + v2 * v2 + v3 * v3;
#pragma unroll
    for (int o = 32; o > 0; o >>= 1) ss += __shfl_xor(ss, o, 64);
    float rs = rsqrtf(fmaxf(ss, 1e-12f));
    float4 o4; o4.x = v0 * rs; o4.y = v1 * rs; o4.z = v2 * rs; o4.w = v3 * rs;
    *(float4*)(out + (size_t)row * PJdim + lane * 4) = o4;
}

// ---------------- persistent kernel: flag-pipelined, no grid.sync, no wbl2 ----------------
// Hazard audit (counters count COMPLETED steps; "done t" = times 0..t-1 finished):
//  gate(l,t) waits: p_done[gid] >= 4t        -> h(l,t-1) ready AND mbuf(l,t-1) consumed (WAR)
//                   p_done[gid-1] >= 4(t+1)  -> h(l-1,t) ready (l>0)
//  proj(l,t) waits: g_done[gid] >= 12(t+1)   -> m(l,t) ready AND gate(l,t)'s h16(l,t-1) reads done (WAR)
//                   g_done[gid+1] >= 12t     -> gate(l+1,t-1) finished reading h(l,t-1) (WAR, l<2)
// DAG: gate(l,t) <- proj(l,t-1), proj(l-1,t); proj(l,t) <- gate(l,t), gate(l+1,t-1): acyclic.
__global__ __launch_bounds__(512)
void lstm_persist(const _Float16* __restrict__ x16, const _Float16* __restrict__ Wfrag,
                  const _Float16* __restrict__ Pfrag,
                  const float* __restrict__ bias0, const float* __restrict__ bias1,
                  const float* __restrict__ bias2,
                  _Float16* __restrict__ h16, _Float16* __restrict__ mbuf,
                  const _Float16* __restrict__ zerop, float* __restrict__ out,
                  unsigned* __restrict__ flags)
{
    __shared__ __align__(16) _Float16 Ast[2 * 8192];   // 32 KiB: double-buffered 64k-chunk
    __shared__ __align__(16) float zst[16 * 256];      // 16 KiB

    const int tid = threadIdx.x, bid = blockIdx.x;
    const int wv = tid >> 6, lane = tid & 63;

    // XCD-grouped role mapping: gid lives on XCD gid>>1 (assuming bid%8=XCD)
    const int xcd = bid & 7, slot = bid >> 3;
    const int gid = xcd * 2 + (slot >> 4);
    const int rr  = slot & 15;
    if (gid >= 15) return;                              // 16 idle blocks exit
    const int bt2 = gid / 3, l = gid % 3;
    const int b0r = bt2 * 128;

    unsigned* gd = flags + (size_t)gid * 64;            // 256B-spread counters
    unsigned* pd = gd + 32;

    if (rr < 12) {                                      // ---- gate block ----
        const int ht = rr, h0 = ht * 64;
        const int KC = (l == 0) ? 10 : 16;
        half8 Breg[16][2];
        load_Breg(Wfrag, l, ht, wv, lane, Breg);
        float bia[2], bja[2], bfa[2], boa[2];
        load_bias((l == 0) ? bias0 : (l == 1) ? bias1 : bias2, h0, tid, bia, bja, bfa, boa);
        float c[8][2];
#pragma unroll
        for (int i = 0; i < 8; ++i) { c[i][0] = 0.f; c[i][1] = 0.f; }
        unsigned* pd_lo = (l > 0) ? flags + (size_t)(gid - 1) * 64 + 32 : nullptr;
        for (int t = 0; t < Tdim; ++t) {
            pipe_wait(pd, 4u * (unsigned)t, pd_lo, (l > 0) ? 4u * (unsigned)(t + 1) : 0u);
            gate_step(l, b0r, h0, KC, t, Breg, c, bia, bja, bfa, boa,
                      x16, h16, zerop, mbuf, Ast, zst, tid);
            pipe_sig(gd);
        }
        if (l == 2 && rr < 8) {                         // finalize: 8 blocks x 16 rows per gid
            pipe_wait(pd, 4u * (unsigned)Tdim, nullptr, 0u);   // same-XCD producer: inv + dirty-L2 read
            int row0 = b0r + rr * 16 + wv * 2;
            finalize_row(h16, out, row0, lane);
            finalize_row(h16, out, row0 + 1, lane);
        }
    } else {                                            // ---- proj block ----
        const int cq = rr - 12;
        // cross-XCD h16 consumer iff gid odd (gid+1 on next XCD), consumer exists:
        const bool xstore = ((gid & 1) == 1) && (gid + 1 < 15) && ((gid + 1) % 3 != 0);
        half8 Preg[24];
        load_Preg(Pfrag, l, cq, wv, lane, Preg);
        unsigned* gd_hi = (l < 2) ? flags + (size_t)(gid + 1) * 64 : nullptr;
        for (int t = 0; t < Tdim; ++t) {
            pipe_wait(gd, 12u * (unsigned)(t + 1), gd_hi, (l < 2) ? 12u * (unsigned)t : 0u);
            proj_step(l, b0r, cq, Preg, mbuf, h16, Ast, tid, xstore);
            pipe_sig(pd);
        }
    }
}

// ---------------- fallback: per-step kernels, c-state in global ----------------
__global__ __launch_bounds__(512)
void gate_fb(const _Float16* __restrict__ x16, const _Float16* __restrict__ Wfrag,
             const float* __restrict__ bias0, const float* __restrict__ bias1,
             const float* __restrict__ bias2,
             _Float16* __restrict__ h16, _Float16* __restrict__ mbuf,
             const _Float16* __restrict__ zerop, float* __restrict__ cfb, int s)
{
    __shared__ __align__(16) _Float16 Ast[2 * 8192];
    __shared__ __align__(16) float zst[16 * 256];
    const int tid = threadIdx.x, bid = blockIdx.x;
    const int ht = bid % 12, z = bid / 12, l = z % 3, bt2 = z / 3;
    const int t = s - l;
    if (t < 0 || t >= Tdim) return;
    const int wv = tid >> 6, lane = tid & 63;
    const int b0r = bt2 * 128, h0 = ht * 64;
    const int KC = (l == 0) ? 10 : 16;
    half8 Breg[16][2];
    load_Breg(Wfrag, l, ht, wv, lane, Breg);
    float bia[2], bja[2], bfa[2], boa[2];
    load_bias((l == 0) ? bias0 : (l == 1) ? bias1 : bias2, h0, tid, bia, bja, bfa, boa);
    const int trow = tid >> 5, hc0 = (tid * 2) & 63;
    float c[8][2];
#pragma unroll
    for (int rf = 0; rf < 8; ++rf)
#pragma unroll
        for (int j = 0; j < 2; ++j)
            c[rf][j] = cfb[((size_t)l * Bdim + b0r + rf * 16 + trow) * Hdim + h0 + hc0 + j];
    gate_step(l, b0r, h0, KC, t, Breg, c, bia, bja, bfa, boa, x16, h16, zerop, mbuf, Ast, zst, tid);
#pragma unroll
    for (int rf = 0; rf < 8; ++rf)
#pragma unroll
        for (int j = 0; j < 2; ++j)
            cfb[((size_t)l * Bdim + b0r + rf * 16 + trow) * Hdim + h0 + hc0 + j] = c[rf][j];
}

__global__ __launch_bounds__(512)
void proj_fb(const _Float16* __restrict__ Pfrag, const _Float16* __restrict__ mbuf,
             _Float16* __restrict__ h16, int s)
{
    __shared__ __align__(16) _Float16 Ast[2 * 8192];
    const int tid = threadIdx.x, bid = blockIdx.x;
    const int cq = bid & 3, z = bid >> 2, l = z % 3, bt2 = z / 3;
    const int tp = s - l;
    if (tp < 0 || tp >= Tdim) return;
    const int wv = tid >> 6, lane = tid & 63;
    half8 Preg[24];
    load_Preg(Pfrag, l, cq, wv, lane, Preg);
    proj_step(l, bt2 * 128, cq, Preg, mbuf, h16, Ast, tid, false);
}

__global__ __launch_bounds__(512)
void fin_fb(const _Float16* __restrict__ h16, float* __restrict__ out)
{
    int row = blockIdx.x * 8 + (threadIdx.x >> 6);
    finalize_row(h16, out, row, threadIdx.x & 63);
}

extern "C" void kernel_launch(void* const* d_in, const int* in_sizes, int n_in,
                              void* d_out, int out_size, void* d_ws, size_t ws_size,
                              hipStream_t stream)
{
    (void)in_sizes; (void)n_in; (void)out_size; (void)ws_size;
    const float* x  = (const float*)d_in[0];
    const float* W0 = (const float*)d_in[1];
    const float* b0 = (const float*)d_in[2];
    const float* P0 = (const float*)d_in[3];
    const float* W1 = (const float*)d_in[4];
    const float* b1 = (const float*)d_in[5];
    const float* P1 = (const float*)d_in[6];
    const float* W2 = (const float*)d_in[7];
    const float* b2 = (const float*)d_in[8];
    const float* P2 = (const float*)d_in[9];

    char* ws = (char*)d_ws;
    _Float16* h16   = (_Float16*)(ws);
    _Float16* zerop = (_Float16*)(ws + ZP_OFF);
    _Float16* mbuf  = (_Float16*)(ws + MB_OFF);
    _Float16* x16   = (_Float16*)(ws + X_OFF);
    _Float16* Wfrag = (_Float16*)(ws + W_OFF);
    _Float16* Pfrag = (_Float16*)(ws + P_OFF);
    float*    cfb   = (float*)(ws + C_OFF);
    unsigned* flags = (unsigned*)(ws + C_OFF);   // coop path only; aliases cfb (fallback-only)
    float*    outp  = (float*)d_out;

    // zero h state + zero page (+ fallback c / pipe flags — same region)
    hipMemsetAsync(ws, 0, ZP_OFF + 256, stream);
    hipMemsetAsync(cfb, 0, C_BYTES, stream);

    {
        constexpr size_t total = W_HALFS + P_HALFS + X_HALFS;
        int grid = (int)((total + 255) / 256);
        repack_kernel<<<grid, 256, 0, stream>>>(x, W0, W1, W2, P0, P1, P2, Wfrag, Pfrag, x16);
    }

    int occ = 0;
    hipError_t oe = hipOccupancyMaxActiveBlocksPerMultiprocessor(&occ, lstm_persist, 512, 0);
    bool coop = (oe == hipSuccess && occ >= 1);
    if (coop) {
        void* args[] = { (void*)&x16, (void*)&Wfrag, (void*)&Pfrag,
                         (void*)&b0, (void*)&b1, (void*)&b2,
                         (void*)&h16, (void*)&mbuf, (void*)&zerop, (void*)&outp,
                         (void*)&flags };
        hipError_t le = hipLaunchCooperativeKernel((const void*)lstm_persist,
                                                   dim3(256), dim3(512), args, 0, stream);
        if (le != hipSuccess) { (void)hipGetLastError(); coop = false; }
    }
    if (!coop) {
        for (int s = 0; s < NSTEP; ++s) {
            gate_fb<<<180, 512, 0, stream>>>(x16, Wfrag, b0, b1, b2, h16, mbuf, zerop, cfb, s);
            proj_fb<<<60, 512, 0, stream>>>(Pfrag, mbuf, h16, s);
        }
        fin_fb<<<80, 512, 0, stream>>>(h16, outp);
    }
}